// Round 1
// baseline (188.970 us; speedup 1.0000x reference)
//
#include <hip/hip_runtime.h>

// ROI Align (FPN, PH=PW=7, SR=2), fp32 I/O.
// R10 = R9 (merged x4 gathers, 71.5us/dispatch) + CPT=4 in the CHANNEL dim.
// Theory: geometry (roi decode, sample coords, weights, window indices) is
// channel-invariant but was recomputed 256x per (roi,pixel). One thread now
// handles channels {c2, c2+64, c2+128, c2+192}: geometry amortized 4x,
// 4x loads-in-flight (batched per sy to cap VGPR), 4x fewer waves.
// The per-load-instruction lane footprint (49 px of one channel + 15 of the
// next) and the store coalescing are IDENTICAL to R9, so line/transaction
// counts per useful byte are unchanged. 64*49=3136 threads/roi = 49 waves
// exactly -> bw branch stays wave-uniform.
// Predicted: dur 71.5 -> ~55us, VALUBusy 53 -> ~40%, FETCH unchanged.

#define NUM_CH 256
#define CPT    4            // channels per thread
#define CGRP   64           // NUM_CH / CPT

typedef float floatx2 __attribute__((ext_vector_type(2)));
typedef float floatx4 __attribute__((ext_vector_type(4)));

__device__ __forceinline__ float ext4(floatx4 v, int i) {
    float r = (i == 1) ? v.y : v.x;
    r = (i == 2) ? v.z : r;
    r = (i == 3) ? v.w : r;
    return r;
}

__global__ __launch_bounds__(256) void roi_align_kernel(
    const float* __restrict__ f0,
    const float* __restrict__ f1,
    const float* __restrict__ f2,
    const float* __restrict__ f3,
    const float* __restrict__ rois_f,
    const int* __restrict__ level,
    float* __restrict__ out,
    int total)                       // total = K * CGRP * 49
{
    int u = blockIdx.x * blockDim.x + threadIdx.x;
    if (u >= total) return;

    int p  = u % 49;           // output pixel (lane-minor, coalesced store)
    int t  = u / 49;
    int c2 = t % CGRP;         // channel group
    int k  = t / CGRP;         // roi
    int ph = p / 7;
    int pw = p % 7;

    int lvl = level[k];
    const float* f;
    int H, W; float scale;
    if (lvl == 0)      { f = f0; H = 200; W = 200; scale = 0.25f;    }
    else if (lvl == 1) { f = f1; H = 100; W = 100; scale = 0.125f;   }
    else if (lvl == 2) { f = f2; H = 50;  W = 50;  scale = 0.0625f;  }
    else               { f = f3; H = 25;  W = 25;  scale = 0.03125f; }

    const float* rf = rois_f + (size_t)k * 5;
    float r0 = rf[0];
    float x1 = rf[1] * scale, y1 = rf[2] * scale;
    float x2 = rf[3] * scale, y2 = rf[4] * scale;
    int bi = (int)r0;
    bi = (bi < 0) ? 0 : ((bi > 1) ? 1 : bi);

    float bh = fmaxf(y2 - y1, 1.0f) * (1.0f / 7.0f);
    float bw = fmaxf(x2 - x1, 1.0f) * (1.0f / 7.0f);

    const size_t plane = (size_t)(H * W);
    const float* base  = f + ((size_t)bi * NUM_CH + c2) * plane;
    const size_t cstr  = (size_t)CGRP * plane;   // stride between my channels

    // ---- factored geometry: 2 y-samples + 2 x-samples (channel-invariant) -
    int   rA[2], rB[2];
    float lyv[2], hyv[2], vy[2];
    #pragma unroll
    for (int sy = 0; sy < 2; ++sy) {
        float y = y1 + (float)ph * bh + ((float)sy + 0.5f) * (bh * 0.5f);
        bool valid = (y > -1.0f) && (y < (float)H);
        float yc = fmaxf(y, 0.0f);
        int yl = min((int)yc, H - 1);
        int yh = min(yl + 1, H - 1);
        float ly = (yl >= H - 1) ? 0.0f : (yc - (float)yl);
        rA[sy] = yl * W;
        rB[sy] = yh * W;
        lyv[sy] = ly; hyv[sy] = 1.0f - ly;
        vy[sy] = valid ? 0.25f : 0.0f;     // fold 2x2 mean into y validity
    }
    int   xlv[2], xhv[2];
    float lxv[2], hxv[2], vx[2];
    #pragma unroll
    for (int sx = 0; sx < 2; ++sx) {
        float x = x1 + (float)pw * bw + ((float)sx + 0.5f) * (bw * 0.5f);
        bool valid = (x > -1.0f) && (x < (float)W);
        float xc = fmaxf(x, 0.0f);
        int xl = min((int)xc, W - 1);
        float lx = (xl >= W - 1) ? 0.0f : (xc - (float)xl);
        xlv[sx] = xl;
        xhv[sx] = min(xl + 1, W - 1);
        lxv[sx] = lx; hxv[sx] = 1.0f - lx;
        vx[sx] = valid ? 1.0f : 0.0f;
    }

    float acc[CPT];
    #pragma unroll
    for (int j = 0; j < CPT; ++j) acc[j] = 0.0f;

    if (bw <= 3.98f) {
        // ---- merged path: x-span of all 4 x-corners fits a 4-float window -
        int xq = min(xlv[0], W - 4);               // window base (>=0: W>=25)
        int i0l = min(max(xlv[0] - xq, 0), 3);
        int i0h = min(max(xhv[0] - xq, 0), 3);
        int i1l = min(max(xlv[1] - xq, 0), 3);
        int i1h = min(max(xhv[1] - xq, 0), 3);

        #pragma unroll
        for (int sy = 0; sy < 2; ++sy) {
            floatx4 LA[CPT], LB[CPT];
            #pragma unroll
            for (int j = 0; j < CPT; ++j) {
                const float* bj = base + (size_t)j * cstr;
                LA[j] = *(const floatx4*)(bj + rA[sy] + xq);  // row yl
                LB[j] = *(const floatx4*)(bj + rB[sy] + xq);  // row yh
            }
            #pragma unroll
            for (int sx = 0; sx < 2; ++sx) {
                int il = sx ? i1l : i0l;
                int ih = sx ? i1h : i0h;
                float vs  = vy[sy] * vx[sx];
                float w00 = hyv[sy] * hxv[sx] * vs;
                float w01 = hyv[sy] * lxv[sx] * vs;
                float w10 = lyv[sy] * hxv[sx] * vs;
                float w11 = lyv[sy] * lxv[sx] * vs;
                #pragma unroll
                for (int j = 0; j < CPT; ++j) {
                    acc[j] += w00 * ext4(LA[j], il) + w01 * ext4(LA[j], ih)
                            + w10 * ext4(LB[j], il) + w11 * ext4(LB[j], ih);
                }
            }
        }
    } else {
        // ---- wide-ROI path: 8 dwordx2 gathers per channel ----------------
        int   xb[2];
        float sel[2];
        #pragma unroll
        for (int sx = 0; sx < 2; ++sx) {
            int xq = min(xlv[sx], W - 2);
            xb[sx]  = xq;
            sel[sx] = (xlv[sx] > xq) ? 1.0f : 0.0f;
        }
        #pragma unroll
        for (int sy = 0; sy < 2; ++sy) {
            floatx2 va[CPT][2], vb[CPT][2];
            #pragma unroll
            for (int sx = 0; sx < 2; ++sx) {
                #pragma unroll
                for (int j = 0; j < CPT; ++j) {
                    const float* bj = base + (size_t)j * cstr;
                    va[j][sx] = *(const floatx2*)(bj + rA[sy] + xb[sx]);
                    vb[j][sx] = *(const floatx2*)(bj + rB[sy] + xb[sx]);
                }
            }
            #pragma unroll
            for (int sx = 0; sx < 2; ++sx) {
                float vs  = vy[sy] * vx[sx];
                float w00 = hyv[sy] * hxv[sx] * vs;
                float w01 = hyv[sy] * lxv[sx] * vs;
                float w10 = lyv[sy] * hxv[sx] * vs;
                float w11 = lyv[sy] * lxv[sx] * vs;
                float s0  = sel[sx];
                #pragma unroll
                for (int j = 0; j < CPT; ++j) {
                    float v00 = va[j][sx].x + s0 * (va[j][sx].y - va[j][sx].x);
                    float v10 = vb[j][sx].x + s0 * (vb[j][sx].y - vb[j][sx].x);
                    acc[j] += w00 * v00 + w01 * va[j][sx].y
                            + w10 * v10 + w11 * vb[j][sx].y;
                }
            }
        }
    }

    size_t ob = ((size_t)k * NUM_CH + c2) * 49 + p;
    #pragma unroll
    for (int j = 0; j < CPT; ++j)
        out[ob + (size_t)j * (CGRP * 49)] = acc[j];
}

extern "C" void kernel_launch(void* const* d_in, const int* in_sizes, int n_in,
                              void* d_out, int out_size, void* d_ws, size_t ws_size,
                              hipStream_t stream) {
    const float* f0   = (const float*)d_in[0];
    const float* f1   = (const float*)d_in[1];
    const float* f2   = (const float*)d_in[2];
    const float* f3   = (const float*)d_in[3];
    const float* rois = (const float*)d_in[4];
    // d_in[5] = rois_counts (unused)
    const int* level = (const int*)d_in[6];
    float* out = (float*)d_out;

    int total = out_size / CPT;   // K * 64 * 49 threads, 4 channels each
    int threads = 256;
    int blocks = (total + threads - 1) / threads;
    roi_align_kernel<<<blocks, threads, 0, stream>>>(f0, f1, f2, f3, rois, level, out, total);
}

// Round 2
// 184.976 us; speedup vs baseline: 1.0216x; 1.0216x over previous
//
#include <hip/hip_runtime.h>

// ROI Align (FPN, PH=PW=7, SR=2), fp32 I/O.
// R11 = R10 datapath + CHANNEL-OUTER / ROI-INNER schedule + chunked XCD swizzle.
// Post-mortem R10: VALUBusy 53->23% with dur flat => VALU not critical path.
// FETCH=192MB vs 108MB total input => every line L2-missed ~2x; R9/R10 have
// equal outstanding-request products and equal time => latency-bound on
// L3-hit (~500cy) loads at a fixed per-CU concurrency ceiling.
// Fix: schedule so each XCD's resident working set fits its private 4MB L2.
//   wave = one (channel-group c2, roi k), lanes 0..48 = the 49 px (15 idle).
//   wave_id = c2*K + k  (c2 outer, k inner);
//   chunked XCD swizzle: XCD x gets c2 in [8x,8x+8) -> per-XCD instantaneous
//   footprint ~2 channel-quads x 425KB = ~3.4MB < 4MB L2. Each feature line
//   fetched once by one XCD; 3.5x ROI over-coverage reuse becomes L2 hits.
// k wave-uniform by construction -> readfirstlane -> scalar roi/level decode.
// Predicted: FETCH 192 -> ~120MB, dur 74 -> ~50us, VALUBusy ~30%.

#define NUM_CH 256
#define CPT    4            // channels per thread
#define CGRP   64           // NUM_CH / CPT

typedef float floatx2 __attribute__((ext_vector_type(2)));
typedef float floatx4 __attribute__((ext_vector_type(4)));

__device__ __forceinline__ float ext4(floatx4 v, int i) {
    float r = (i == 1) ? v.y : v.x;
    r = (i == 2) ? v.z : r;
    r = (i == 3) ? v.w : r;
    return r;
}

__global__ __launch_bounds__(256) void roi_align_kernel(
    const float* __restrict__ f0,
    const float* __restrict__ f1,
    const float* __restrict__ f2,
    const float* __restrict__ f3,
    const float* __restrict__ rois_f,
    const int* __restrict__ level,
    float* __restrict__ out,
    int K,                           // number of rois
    int NW)                          // total waves = K * CGRP
{
    // ---- chunked XCD swizzle: physical block b -> logical block l ---------
    // HW round-robins blocks across 8 XCDs (b % 8). Give XCD x a CONTIGUOUS
    // logical range so its L2 sees a small, stable channel slice.
    int nb  = gridDim.x;
    int q   = nb >> 3, r = nb & 7;
    int xcd = blockIdx.x & 7;
    int idx = blockIdx.x >> 3;
    int l   = xcd * q + min(xcd, r) + idx;          // bijective for any nb

    int wid = l * 4 + (int)(threadIdx.x >> 6);      // logical wave id
    if (wid >= NW) return;
    int lane = threadIdx.x & 63;
    if (lane >= 49) return;                         // 49 px per wave

    int k  = wid % K;                               // roi   (inner)
    int c2 = wid / K;                               // cgrp  (outer)
    k  = __builtin_amdgcn_readfirstlane(k);         // wave-uniform -> SGPR
    c2 = __builtin_amdgcn_readfirstlane(c2);

    int p  = lane;
    int ph = p / 7;
    int pw = p % 7;

    int lvl = level[k];
    const float* f;
    int H, W; float scale;
    if (lvl == 0)      { f = f0; H = 200; W = 200; scale = 0.25f;    }
    else if (lvl == 1) { f = f1; H = 100; W = 100; scale = 0.125f;   }
    else if (lvl == 2) { f = f2; H = 50;  W = 50;  scale = 0.0625f;  }
    else               { f = f3; H = 25;  W = 25;  scale = 0.03125f; }

    const float* rf = rois_f + (size_t)k * 5;
    float r0 = rf[0];
    float x1 = rf[1] * scale, y1 = rf[2] * scale;
    float x2 = rf[3] * scale, y2 = rf[4] * scale;
    int bi = (int)r0;
    bi = (bi < 0) ? 0 : ((bi > 1) ? 1 : bi);

    float bh = fmaxf(y2 - y1, 1.0f) * (1.0f / 7.0f);
    float bw = fmaxf(x2 - x1, 1.0f) * (1.0f / 7.0f);

    const size_t plane = (size_t)(H * W);
    const float* base  = f + ((size_t)bi * NUM_CH + c2) * plane;
    const size_t cstr  = (size_t)CGRP * plane;   // stride between my channels

    // ---- factored geometry: 2 y-samples + 2 x-samples (channel-invariant) -
    int   rA[2], rB[2];
    float lyv[2], hyv[2], vy[2];
    #pragma unroll
    for (int sy = 0; sy < 2; ++sy) {
        float y = y1 + (float)ph * bh + ((float)sy + 0.5f) * (bh * 0.5f);
        bool valid = (y > -1.0f) && (y < (float)H);
        float yc = fmaxf(y, 0.0f);
        int yl = min((int)yc, H - 1);
        int yh = min(yl + 1, H - 1);
        float ly = (yl >= H - 1) ? 0.0f : (yc - (float)yl);
        rA[sy] = yl * W;
        rB[sy] = yh * W;
        lyv[sy] = ly; hyv[sy] = 1.0f - ly;
        vy[sy] = valid ? 0.25f : 0.0f;     // fold 2x2 mean into y validity
    }
    int   xlv[2], xhv[2];
    float lxv[2], hxv[2], vx[2];
    #pragma unroll
    for (int sx = 0; sx < 2; ++sx) {
        float x = x1 + (float)pw * bw + ((float)sx + 0.5f) * (bw * 0.5f);
        bool valid = (x > -1.0f) && (x < (float)W);
        float xc = fmaxf(x, 0.0f);
        int xl = min((int)xc, W - 1);
        float lx = (xl >= W - 1) ? 0.0f : (xc - (float)xl);
        xlv[sx] = xl;
        xhv[sx] = min(xl + 1, W - 1);
        lxv[sx] = lx; hxv[sx] = 1.0f - lx;
        vx[sx] = valid ? 1.0f : 0.0f;
    }

    float acc[CPT];
    #pragma unroll
    for (int j = 0; j < CPT; ++j) acc[j] = 0.0f;

    if (bw <= 3.98f) {
        // ---- merged path: x-span of all 4 x-corners fits a 4-float window -
        int xq = min(xlv[0], W - 4);               // window base (>=0: W>=25)
        int i0l = min(max(xlv[0] - xq, 0), 3);
        int i0h = min(max(xhv[0] - xq, 0), 3);
        int i1l = min(max(xlv[1] - xq, 0), 3);
        int i1h = min(max(xhv[1] - xq, 0), 3);

        #pragma unroll
        for (int sy = 0; sy < 2; ++sy) {
            floatx4 LA[CPT], LB[CPT];
            #pragma unroll
            for (int j = 0; j < CPT; ++j) {
                const float* bj = base + (size_t)j * cstr;
                LA[j] = *(const floatx4*)(bj + rA[sy] + xq);  // row yl
                LB[j] = *(const floatx4*)(bj + rB[sy] + xq);  // row yh
            }
            #pragma unroll
            for (int sx = 0; sx < 2; ++sx) {
                int il = sx ? i1l : i0l;
                int ih = sx ? i1h : i0h;
                float vs  = vy[sy] * vx[sx];
                float w00 = hyv[sy] * hxv[sx] * vs;
                float w01 = hyv[sy] * lxv[sx] * vs;
                float w10 = lyv[sy] * hxv[sx] * vs;
                float w11 = lyv[sy] * lxv[sx] * vs;
                #pragma unroll
                for (int j = 0; j < CPT; ++j) {
                    acc[j] += w00 * ext4(LA[j], il) + w01 * ext4(LA[j], ih)
                            + w10 * ext4(LB[j], il) + w11 * ext4(LB[j], ih);
                }
            }
        }
    } else {
        // ---- wide-ROI path: 8 dwordx2 gathers per channel ----------------
        int   xb[2];
        float sel[2];
        #pragma unroll
        for (int sx = 0; sx < 2; ++sx) {
            int xq = min(xlv[sx], W - 2);
            xb[sx]  = xq;
            sel[sx] = (xlv[sx] > xq) ? 1.0f : 0.0f;
        }
        #pragma unroll
        for (int sy = 0; sy < 2; ++sy) {
            floatx2 va[CPT][2], vb[CPT][2];
            #pragma unroll
            for (int sx = 0; sx < 2; ++sx) {
                #pragma unroll
                for (int j = 0; j < CPT; ++j) {
                    const float* bj = base + (size_t)j * cstr;
                    va[j][sx] = *(const floatx2*)(bj + rA[sy] + xb[sx]);
                    vb[j][sx] = *(const floatx2*)(bj + rB[sy] + xb[sx]);
                }
            }
            #pragma unroll
            for (int sx = 0; sx < 2; ++sx) {
                float vs  = vy[sy] * vx[sx];
                float w00 = hyv[sy] * hxv[sx] * vs;
                float w01 = hyv[sy] * lxv[sx] * vs;
                float w10 = lyv[sy] * hxv[sx] * vs;
                float w11 = lyv[sy] * lxv[sx] * vs;
                float s0  = sel[sx];
                #pragma unroll
                for (int j = 0; j < CPT; ++j) {
                    float v00 = va[j][sx].x + s0 * (va[j][sx].y - va[j][sx].x);
                    float v10 = vb[j][sx].x + s0 * (vb[j][sx].y - vb[j][sx].x);
                    acc[j] += w00 * v00 + w01 * va[j][sx].y
                            + w10 * v10 + w11 * vb[j][sx].y;
                }
            }
        }
    }

    size_t ob = ((size_t)k * NUM_CH + c2) * 49 + p;
    #pragma unroll
    for (int j = 0; j < CPT; ++j)
        out[ob + (size_t)j * (CGRP * 49)] = acc[j];
}

extern "C" void kernel_launch(void* const* d_in, const int* in_sizes, int n_in,
                              void* d_out, int out_size, void* d_ws, size_t ws_size,
                              hipStream_t stream) {
    const float* f0   = (const float*)d_in[0];
    const float* f1   = (const float*)d_in[1];
    const float* f2   = (const float*)d_in[2];
    const float* f3   = (const float*)d_in[3];
    const float* rois = (const float*)d_in[4];
    // d_in[5] = rois_counts (unused)
    const int* level = (const int*)d_in[6];
    float* out = (float*)d_out;

    int K  = out_size / (NUM_CH * 49);   // rois
    int NW = K * CGRP;                   // one wave per (channel-group, roi)
    int threads = 256;                   // 4 waves per block
    int blocks  = (NW + 3) / 4;
    roi_align_kernel<<<blocks, threads, 0, stream>>>(f0, f1, f2, f3, rois, level, out, K, NW);
}